// Round 1
// baseline (332.181 us; speedup 1.0000x reference)
//
#include <hip/hip_runtime.h>
#include <hip/hip_bf16.h>

typedef __bf16 bf16;
typedef __attribute__((ext_vector_type(8))) __bf16 bf16x8;
typedef __attribute__((ext_vector_type(4))) float f32x4;

namespace {
constexpr int CH   = 64;
constexpr int SEQ  = 2048;
constexpr int TQ   = 64;
constexpr int TS   = 64;
constexpr int CPAD = CH + 8;   // 72 bf16 -> 144B rows: 16B-aligned, ~2-way bank conflicts
constexpr int SPAD = TS + 8;   // 72
constexpr int OPAD = TQ + 4;   // 68 f32 -> 272B rows: 16B-aligned
}

__global__ __launch_bounds__(256, 2)
void qkv_attn_kernel(const float* __restrict__ qkv, float* __restrict__ out) {
    const int bid  = blockIdx.x;
    const int head = bid >> 5;            // 32 t-tiles per head
    const int t0   = (bid & 31) * TQ;
    const int tid  = threadIdx.x;
    const int lane = tid & 63;
    const int w    = tid >> 6;            // wave 0..3, owns t rows [w*16, w*16+16)
    const int g    = lane >> 4;           // 0..3
    const int lr   = lane & 15;

    // carve one LDS block so the epilogue can overlay the Q/K region
    __shared__ __align__(16) char smem_raw[(TQ*CPAD + TS*CPAD + CH*SPAD + TQ*SPAD) * 2];
    bf16 (*Qs)[CPAD] = (bf16(*)[CPAD])(smem_raw);                                   // [t][c]
    bf16 (*Ks)[CPAD] = (bf16(*)[CPAD])(smem_raw + TQ*CPAD*2);                       // [s][c]
    bf16 (*Vs)[SPAD] = (bf16(*)[SPAD])(smem_raw + (TQ*CPAD + TS*CPAD)*2);           // [c][s]
    bf16 (*Ps)[SPAD] = (bf16(*)[SPAD])(smem_raw + (TQ*CPAD + TS*CPAD + CH*SPAD)*2); // [t][s]
    float* Os = (float*)smem_raw;  // epilogue [CH][OPAD] f32 = 17408B <= Qs+Ks (18432B)

    const float* qbase = qkv + (size_t)(head*192 +   0) * SEQ;
    const float* kbase = qkv + (size_t)(head*192 +  64) * SEQ;
    const float* vbase = qkv + (size_t)(head*192 + 128) * SEQ;

    // ---- stage Q once: global (c,t) -> LDS [t][c], fold in scale^2 = 1/sqrt(ch) = 0.125
    {
        const int c0 = tid >> 4;
        const int t4 = (tid & 15) * 4;
        #pragma unroll
        for (int it = 0; it < 4; ++it) {
            const int c = c0 + it*16;
            const float4 v = *(const float4*)(qbase + (size_t)c * SEQ + t0 + t4);
            Qs[t4+0][c] = (bf16)(v.x * 0.125f);
            Qs[t4+1][c] = (bf16)(v.y * 0.125f);
            Qs[t4+2][c] = (bf16)(v.z * 0.125f);
            Qs[t4+3][c] = (bf16)(v.w * 0.125f);
        }
    }

    float m_r[4], l_r[4];
    f32x4 oacc[4];
    #pragma unroll
    for (int r = 0; r < 4; ++r) { m_r[r] = -1e30f; l_r[r] = 0.f; }
    #pragma unroll
    for (int f = 0; f < 4; ++f) oacc[f] = f32x4{0.f, 0.f, 0.f, 0.f};

    for (int s0 = 0; s0 < SEQ; s0 += TS) {
        __syncthreads();   // previous iter's MFMAs done before K/V overwrite
        // ---- stage K: global (c,s) -> LDS [s][c];  V: (c,s) -> [c][s]
        {
            const int c0 = tid >> 4;
            const int s4 = (tid & 15) * 4;
            #pragma unroll
            for (int it = 0; it < 4; ++it) {
                const int c = c0 + it*16;
                const float4 kv = *(const float4*)(kbase + (size_t)c * SEQ + s0 + s4);
                Ks[s4+0][c] = (bf16)kv.x;
                Ks[s4+1][c] = (bf16)kv.y;
                Ks[s4+2][c] = (bf16)kv.z;
                Ks[s4+3][c] = (bf16)kv.w;
                const float4 vv = *(const float4*)(vbase + (size_t)c * SEQ + s0 + s4);
                union { bf16 h[4]; uint2 u; } pk;
                pk.h[0] = (bf16)vv.x; pk.h[1] = (bf16)vv.y;
                pk.h[2] = (bf16)vv.z; pk.h[3] = (bf16)vv.w;
                *(uint2*)&Vs[c][s4] = pk.u;
            }
        }
        __syncthreads();

        // ---- S(t,s) = Q^T K : A[t][c] from Qs, B[c][s] from Ks
        // D layout (verified): row t_local = 4g+r, col s_local = lr (+16f)
        f32x4 sacc[4];
        #pragma unroll
        for (int f = 0; f < 4; ++f) sacc[f] = f32x4{0.f,0.f,0.f,0.f};
        #pragma unroll
        for (int ks = 0; ks < 2; ++ks) {
            const bf16x8 aq = *(const bf16x8*)&Qs[w*16 + lr][ks*32 + g*8];
            #pragma unroll
            for (int f = 0; f < 4; ++f) {
                const bf16x8 bk = *(const bf16x8*)&Ks[f*16 + lr][ks*32 + g*8];
                sacc[f] = __builtin_amdgcn_mfma_f32_16x16x32_bf16(aq, bk, sacc[f], 0, 0, 0);
            }
        }

        // ---- online softmax (rows t = w*16 + 4g + r; cols spread over 16-lane group)
        float tm[4], alpha[4], rs[4];
        #pragma unroll
        for (int r = 0; r < 4; ++r)
            tm[r] = fmaxf(fmaxf(sacc[0][r], sacc[1][r]), fmaxf(sacc[2][r], sacc[3][r]));
        #pragma unroll
        for (int mask = 1; mask <= 8; mask <<= 1) {
            #pragma unroll
            for (int r = 0; r < 4; ++r)
                tm[r] = fmaxf(tm[r], __shfl_xor(tm[r], mask));
        }
        #pragma unroll
        for (int r = 0; r < 4; ++r) {
            const float mn = fmaxf(m_r[r], tm[r]);
            alpha[r] = __expf(m_r[r] - mn);
            m_r[r]   = mn;
            float acc = 0.f;
            #pragma unroll
            for (int f = 0; f < 4; ++f) {
                const float p = __expf(sacc[f][r] - mn);
                sacc[f][r] = p;
                acc += p;
            }
            rs[r] = acc;
        }
        #pragma unroll
        for (int mask = 1; mask <= 8; mask <<= 1) {
            #pragma unroll
            for (int r = 0; r < 4; ++r)
                rs[r] += __shfl_xor(rs[r], mask);
        }
        #pragma unroll
        for (int r = 0; r < 4; ++r)
            l_r[r] = l_r[r] * alpha[r] + rs[r];
        #pragma unroll
        for (int f = 0; f < 4; ++f)
            #pragma unroll
            for (int r = 0; r < 4; ++r)
                oacc[f][r] *= alpha[r];

        // ---- P -> LDS (bf16), wave-private rows
        #pragma unroll
        for (int f = 0; f < 4; ++f)
            #pragma unroll
            for (int r = 0; r < 4; ++r)
                Ps[w*16 + g*4 + r][f*16 + lr] = (bf16)sacc[f][r];

        __syncthreads();

        // ---- O^T(t,c) += P(t,s) * V^T(s,c): A[t][s] from Ps, B[s][c] from Vs
        // D rows = same 4g+r as softmax state -> rescale needed no shuffles
        #pragma unroll
        for (int ks = 0; ks < 2; ++ks) {
            const bf16x8 ap = *(const bf16x8*)&Ps[w*16 + lr][ks*32 + g*8];
            #pragma unroll
            for (int f = 0; f < 4; ++f) {
                const bf16x8 bv = *(const bf16x8*)&Vs[f*16 + lr][ks*32 + g*8];
                oacc[f] = __builtin_amdgcn_mfma_f32_16x16x32_bf16(ap, bv, oacc[f], 0, 0, 0);
            }
        }
    }

    // ---- epilogue: normalize, transpose via LDS, coalesced f32 writes
    __syncthreads();
    #pragma unroll
    for (int r = 0; r < 4; ++r) {
        const float inv = 1.0f / l_r[r];
        #pragma unroll
        for (int f = 0; f < 4; ++f)
            Os[(f*16 + lr) * OPAD + (w*16 + g*4 + r)] = oacc[f][r] * inv;
    }
    __syncthreads();
    {
        const int c0 = tid >> 4;
        const int t4 = (tid & 15) * 4;
        #pragma unroll
        for (int it = 0; it < 4; ++it) {
            const int c = c0 + it*16;
            *(float4*)(out + (size_t)(head*64 + c) * SEQ + t0 + t4) =
                *(const float4*)&Os[c * OPAD + t4];
        }
    }
}

extern "C" void kernel_launch(void* const* d_in, const int* in_sizes, int n_in,
                              void* d_out, int out_size, void* d_ws, size_t ws_size,
                              hipStream_t stream) {
    const float* qkv = (const float*)d_in[0];
    float* out = (float*)d_out;
    // 64 heads x 32 q-tiles
    qkv_attn_kernel<<<dim3(2048), dim3(256), 0, stream>>>(qkv, out);
}

// Round 2
// 245.176 us; speedup vs baseline: 1.3549x; 1.3549x over previous
//
#include <hip/hip_runtime.h>
#include <hip/hip_bf16.h>

typedef __bf16 bf16;
typedef __attribute__((ext_vector_type(8))) __bf16 bf16x8;
typedef __attribute__((ext_vector_type(4))) float f32x4;

namespace {
constexpr int SEQ  = 2048;
constexpr int TQ   = 64;
constexpr int TS   = 64;
constexpr int ROWB = 144;   // Q/K row pitch bytes: 8 chunks of 16B used + 1 pad chunk
constexpr int SPAD = 72;    // V/P row pitch (bf16 elements)
constexpr int OPAD = 68;    // epilogue f32 row pitch
}

__global__ __launch_bounds__(256, 4)
void qkv_attn_kernel(const float* __restrict__ qkv, float* __restrict__ out) {
    const int bid  = blockIdx.x;
    const int head = bid >> 5;            // 32 t-tiles per head
    const int t0   = (bid & 31) * TQ;
    const int tid  = threadIdx.x;
    const int lane = tid & 63;
    const int w    = tid >> 6;            // wave 0..3
    const int g    = lane >> 4;           // 0..3
    const int lr   = lane & 15;

    __shared__ __align__(16) char smem[4 * 64 * 144];          // 36864 B
    char* Qb = smem;                                            // [64 rows][144B] swizzled
    char* Kb = smem + 9216;                                     // [64 rows][144B] swizzled
    bf16 (*Vs)[SPAD] = (bf16(*)[SPAD])(smem + 18432);           // [c][s]
    bf16 (*Ps)[SPAD] = (bf16(*)[SPAD])(smem + 27648);           // [t][s]
    float* Os = (float*)smem;                                   // epilogue [64][OPAD] = 17408B

    const float* qbase = qkv + (size_t)(head*192 +   0) * SEQ + t0;
    const float* kbase = qkv + (size_t)(head*192 +  64) * SEQ;
    const float* vbase = qkv + (size_t)(head*192 + 128) * SEQ;

    // staging decomposition: thread -> (c = (tid>>4)+16it, rows r4..r4+3)
    const int cs0 = tid >> 4;
    const int m   = tid & 15;
    const int r4  = m * 4;
    const int sx  = m & 7;     // == ((r4+j)>>2)&7 for j=0..3

    // ---- stage Q once (scale^2 = 1/8 folded), swizzled scalar writes
    #pragma unroll
    for (int it = 0; it < 4; ++it) {
        const int c = cs0 + it*16;
        const float4 v = *(const float4*)(qbase + (size_t)c * SEQ + r4);
        const int coff = ((((c >> 3) ^ sx) << 4) | ((c & 7) << 1));
        *(bf16*)(Qb + (r4+0)*ROWB + coff) = (bf16)(v.x * 0.125f);
        *(bf16*)(Qb + (r4+1)*ROWB + coff) = (bf16)(v.y * 0.125f);
        *(bf16*)(Qb + (r4+2)*ROWB + coff) = (bf16)(v.z * 0.125f);
        *(bf16*)(Qb + (r4+3)*ROWB + coff) = (bf16)(v.w * 0.125f);
    }
    __syncthreads();

    // ---- hoist Q fragments (loop-invariant): lane holds row t=w*16+lr, k-chunk (ks,g)
    bf16x8 aq[2];
    {
        const int trow = w*16 + lr;
        const int tx = (trow >> 2) & 7;
        #pragma unroll
        for (int ks = 0; ks < 2; ++ks)
            aq[ks] = *(const bf16x8*)(Qb + trow*ROWB + ((((ks<<2)|g) ^ tx) << 4));
    }

    // ---- prefetch tile 0 K/V into registers
    float4 kf[4], vf[4];
    #pragma unroll
    for (int it = 0; it < 4; ++it) {
        const int c = cs0 + it*16;
        kf[it] = *(const float4*)(kbase + (size_t)c * SEQ + r4);
        vf[it] = *(const float4*)(vbase + (size_t)c * SEQ + r4);
    }

    float m_r[4], l_r[4];
    f32x4 oacc[4];
    #pragma unroll
    for (int r = 0; r < 4; ++r) { m_r[r] = -1e30f; l_r[r] = 0.f; }
    #pragma unroll
    for (int f = 0; f < 4; ++f) oacc[f] = f32x4{0.f, 0.f, 0.f, 0.f};

    for (int s0 = 0; s0 < SEQ; s0 += TS) {
        // ---- regs -> LDS (K swizzled scalar, V packed uint2)
        #pragma unroll
        for (int it = 0; it < 4; ++it) {
            const int c = cs0 + it*16;
            const int coff = ((((c >> 3) ^ sx) << 4) | ((c & 7) << 1));
            *(bf16*)(Kb + (r4+0)*ROWB + coff) = (bf16)kf[it].x;
            *(bf16*)(Kb + (r4+1)*ROWB + coff) = (bf16)kf[it].y;
            *(bf16*)(Kb + (r4+2)*ROWB + coff) = (bf16)kf[it].z;
            *(bf16*)(Kb + (r4+3)*ROWB + coff) = (bf16)kf[it].w;
            union { bf16 h[4]; uint2 u; } pk;
            pk.h[0] = (bf16)vf[it].x; pk.h[1] = (bf16)vf[it].y;
            pk.h[2] = (bf16)vf[it].z; pk.h[3] = (bf16)vf[it].w;
            *(uint2*)&Vs[c][r4] = pk.u;
        }
        __syncthreads();

        // ---- issue next tile's global loads; they drain at next write phase
        if (s0 + TS < SEQ) {
            #pragma unroll
            for (int it = 0; it < 4; ++it) {
                const int c = cs0 + it*16;
                kf[it] = *(const float4*)(kbase + (size_t)c * SEQ + (s0 + TS) + r4);
                vf[it] = *(const float4*)(vbase + (size_t)c * SEQ + (s0 + TS) + r4);
            }
        }

        // ---- S(t,s) = Q^T K ; D: row t_local = 4g+r, col s_local = lr (+16f)
        f32x4 sacc[4];
        #pragma unroll
        for (int f = 0; f < 4; ++f) sacc[f] = f32x4{0.f,0.f,0.f,0.f};
        #pragma unroll
        for (int ks = 0; ks < 2; ++ks) {
            #pragma unroll
            for (int f = 0; f < 4; ++f) {
                const int srow = f*16 + lr;
                const bf16x8 bk = *(const bf16x8*)(Kb + srow*ROWB +
                                    ((((ks<<2)|g) ^ ((srow>>2)&7)) << 4));
                sacc[f] = __builtin_amdgcn_mfma_f32_16x16x32_bf16(aq[ks], bk, sacc[f], 0, 0, 0);
            }
        }

        // ---- online softmax (rows t = w*16 + 4g + r; cols across the 16-lane group)
        float tm[4], alpha[4], rs[4];
        #pragma unroll
        for (int r = 0; r < 4; ++r)
            tm[r] = fmaxf(fmaxf(sacc[0][r], sacc[1][r]), fmaxf(sacc[2][r], sacc[3][r]));
        #pragma unroll
        for (int mask = 1; mask <= 8; mask <<= 1) {
            #pragma unroll
            for (int r = 0; r < 4; ++r)
                tm[r] = fmaxf(tm[r], __shfl_xor(tm[r], mask));
        }
        #pragma unroll
        for (int r = 0; r < 4; ++r) {
            const float mn = fmaxf(m_r[r], tm[r]);
            alpha[r] = __expf(m_r[r] - mn);
            m_r[r]   = mn;
            float acc = 0.f;
            #pragma unroll
            for (int f = 0; f < 4; ++f) {
                const float p = __expf(sacc[f][r] - mn);
                sacc[f][r] = p;
                acc += p;
            }
            rs[r] = acc;
        }
        #pragma unroll
        for (int mask = 1; mask <= 8; mask <<= 1) {
            #pragma unroll
            for (int r = 0; r < 4; ++r)
                rs[r] += __shfl_xor(rs[r], mask);
        }
        #pragma unroll
        for (int r = 0; r < 4; ++r)
            l_r[r] = l_r[r] * alpha[r] + rs[r];
        #pragma unroll
        for (int f = 0; f < 4; ++f)
            #pragma unroll
            for (int r = 0; r < 4; ++r)
                oacc[f][r] *= alpha[r];

        // ---- P -> LDS (wave-private rows: no barrier needed before PV)
        #pragma unroll
        for (int f = 0; f < 4; ++f)
            #pragma unroll
            for (int r = 0; r < 4; ++r)
                Ps[w*16 + g*4 + r][f*16 + lr] = (bf16)sacc[f][r];

        // ---- O(t,c) += P(t,s) V^T(s,c); D rows match softmax rows
        #pragma unroll
        for (int ks = 0; ks < 2; ++ks) {
            const bf16x8 ap = *(const bf16x8*)&Ps[w*16 + lr][ks*32 + g*8];
            #pragma unroll
            for (int f = 0; f < 4; ++f) {
                const bf16x8 bv = *(const bf16x8*)&Vs[f*16 + lr][ks*32 + g*8];
                oacc[f] = __builtin_amdgcn_mfma_f32_16x16x32_bf16(ap, bv, oacc[f], 0, 0, 0);
            }
        }
        __syncthreads();   // all waves done reading Kb/Vs before next overwrite
    }

    // ---- epilogue: normalize, transpose via LDS (overlays Qb/Kb), coalesced writes
    #pragma unroll
    for (int r = 0; r < 4; ++r) {
        const float inv = 1.0f / l_r[r];
        #pragma unroll
        for (int f = 0; f < 4; ++f)
            Os[(f*16 + lr) * OPAD + (w*16 + g*4 + r)] = oacc[f][r] * inv;
    }
    __syncthreads();
    #pragma unroll
    for (int it = 0; it < 4; ++it) {
        const int c = cs0 + it*16;
        *(float4*)(out + (size_t)(head*64 + c) * SEQ + t0 + r4) =
            *(const float4*)&Os[c * OPAD + r4];
    }
}

extern "C" void kernel_launch(void* const* d_in, const int* in_sizes, int n_in,
                              void* d_out, int out_size, void* d_ws, size_t ws_size,
                              hipStream_t stream) {
    const float* qkv = (const float*)d_in[0];
    float* out = (float*)d_out;
    qkv_attn_kernel<<<dim3(2048), dim3(256), 0, stream>>>(qkv, out);
}